// Round 8
// baseline (476.604 us; speedup 1.0000x reference)
//
#include <hip/hip_runtime.h>

#define N_NODES 100000
#define F_IN    256
#define H_DIM   128
#define C_DIM   64
#define E_EDGES 1600000
#define EP_EDGES 500000

#define NBUK 391          // buckets of 256 nodes: bucket = dst >> 8
#define EPB  4096         // edges per bucket-pass block

typedef unsigned short bf16_t;
typedef short  short8  __attribute__((ext_vector_type(8)));
typedef float  float4v __attribute__((ext_vector_type(4)));

__device__ inline bf16_t f2bf(float f) {          // round-to-nearest-even
    unsigned u = __float_as_uint(f);
    u += 0x7fff + ((u >> 16) & 1);
    return (bf16_t)(u >> 16);
}
__device__ inline float bf2f(bf16_t h) {
    return __uint_as_float(((unsigned)h) << 16);
}
__device__ inline void split8(const float* vv, short8* h, short8* l) {
#pragma unroll
    for (int j = 0; j < 8; ++j) {
        bf16_t hb = f2bf(vv[j]);
        (*h)[j] = (short)hb;
        (*l)[j] = (short)f2bf(vv[j] - bf2f(hb));
    }
}
__device__ inline float4v mfma16(short8 a, short8 b, float4v c) {
    return __builtin_amdgcn_mfma_f32_16x16x32_bf16(a, b, c, 0, 0, 0);
}

// ---------------------------------------------------------------------------
// CSR build v2: bucket hist -> bucket scan -> bucket scatter -> bucket sort
// ---------------------------------------------------------------------------
__global__ __launch_bounds__(256) void bhist_kernel(const int* __restrict__ dst,
                                                    int* __restrict__ bsize) {
    __shared__ int hist[NBUK];
    const int t = threadIdx.x;
    for (int b = t; b < NBUK; b += 256) hist[b] = 0;
    __syncthreads();
    const int e0 = blockIdx.x * EPB;
#pragma unroll
    for (int i = 0; i < 16; ++i) {
        int e = e0 + i * 256 + t;
        if (e < E_EDGES) atomicAdd(&hist[dst[e] >> 8], 1);
    }
    __syncthreads();
    for (int b = t; b < NBUK; b += 256)
        if (hist[b]) atomicAdd(&bsize[b], hist[b]);
}

__global__ __launch_bounds__(512) void bscan_kernel(const int* __restrict__ bsize,
                                                    int* __restrict__ bbase,
                                                    int* __restrict__ bcursor) {
    __shared__ int sh[512];
    int t = threadIdx.x;
    sh[t] = (t < NBUK) ? bsize[t] : 0;
    __syncthreads();
#pragma unroll
    for (int off = 1; off < 512; off <<= 1) {
        int u = (t >= off) ? sh[t - off] : 0;
        __syncthreads();
        sh[t] += u;
        __syncthreads();
    }
    if (t < NBUK) {
        int ex = (t == 0) ? 0 : sh[t - 1];
        bbase[t] = ex;
        bcursor[t] = ex;
    }
    if (t == 0) bbase[NBUK] = E_EDGES;
}

__global__ __launch_bounds__(256) void bucket_scatter_kernel(const int* __restrict__ src,
                                                             const int* __restrict__ dst,
                                                             int* __restrict__ bcursor,
                                                             int2* __restrict__ pairs) {
    __shared__ int hist[NBUK];
    __shared__ int base[NBUK];
    const int t = threadIdx.x;
    for (int b = t; b < NBUK; b += 256) hist[b] = 0;
    __syncthreads();

    const int e0 = blockIdx.x * EPB;
    int s[16], d[16];
#pragma unroll
    for (int i = 0; i < 16; ++i) {
        int e = e0 + i * 256 + t;
        if (e < E_EDGES) {
            s[i] = src[e];
            d[i] = dst[e];
            atomicAdd(&hist[d[i] >> 8], 1);
        } else {
            d[i] = -1;
        }
    }
    __syncthreads();
    for (int b = t; b < NBUK; b += 256) {
        int c = hist[b];
        base[b] = c ? atomicAdd(&bcursor[b], c) : 0;
        hist[b] = 0;  // reuse as rank counter
    }
    __syncthreads();
#pragma unroll
    for (int i = 0; i < 16; ++i) {
        if (d[i] >= 0) {
            int b = d[i] >> 8;
            int r = atomicAdd(&hist[b], 1);
            pairs[base[b] + r] = make_int2(s[i], d[i]);
        }
    }
}

// One block per bucket: LDS-count nodes, emit dis + row_ptr, counting-sort csr.
__global__ __launch_bounds__(256) void bucket_sort_kernel(const int2* __restrict__ pairs,
                                                          const int* __restrict__ bbase,
                                                          int* __restrict__ row_ptr,
                                                          float* __restrict__ dis,
                                                          int* __restrict__ csr_src) {
    __shared__ int cnt[256];
    __shared__ int sh[256];
    __shared__ int cur[256];
    const int b = blockIdx.x;
    const int node0 = b << 8;
    const int t = threadIdx.x;
    const int nn = min(256, N_NODES - node0);
    const int beg = bbase[b], end = bbase[b + 1];
    cnt[t] = 0;
    __syncthreads();
    for (int e = beg + t; e < end; e += 256)
        atomicAdd(&cnt[pairs[e].y - node0], 1);
    __syncthreads();
    int c = cnt[t];
    if (t < nn) dis[node0 + t] = rsqrtf((float)c + 1.0f);
    sh[t] = c;
    __syncthreads();
#pragma unroll
    for (int off = 1; off < 256; off <<= 1) {
        int u = (t >= off) ? sh[t - off] : 0;
        __syncthreads();
        sh[t] += u;
        __syncthreads();
    }
    int start = beg + sh[t] - c;   // exclusive prefix
    if (t < nn) row_ptr[node0 + t] = start;
    cur[t] = start;
    if (b == NBUK - 1 && t == 0) row_ptr[N_NODES] = E_EDGES;
    __syncthreads();
    for (int e = beg + t; e < end; e += 256) {
        int2 p = pairs[e];
        int j = atomicAdd(&cur[p.y - node0], 1);
        csr_src[j] = p.x;
    }
}

// ---------------------------------------------------------------------------
// Weight prep: Wt[n][k] bf16 hi/lo splits for both layers (one-time, tiny)
// ---------------------------------------------------------------------------
__global__ __launch_bounds__(256) void wprep_kernel(const float* __restrict__ W1,
                                                    const float* __restrict__ W2,
                                                    short* __restrict__ w1h,
                                                    short* __restrict__ w1l,
                                                    short* __restrict__ w2h,
                                                    short* __restrict__ w2l) {
    int idx = blockIdx.x * 256 + threadIdx.x;
    if (idx < H_DIM * F_IN) {                    // W1t[n=128][k=256]
        int n = idx >> 8, k = idx & 255;
        float w = W1[k * H_DIM + n];
        bf16_t h = f2bf(w);
        w1h[idx] = (short)h;
        w1l[idx] = (short)f2bf(w - bf2f(h));
    }
    int i2 = idx - H_DIM * F_IN;
    if (i2 >= 0 && i2 < C_DIM * H_DIM) {         // W2t[n=64][k=128]
        int n = i2 >> 7, k = i2 & 127;
        float w = W2[k * C_DIM + n];
        bf16_t h = f2bf(w);
        w2h[i2] = (short)h;
        w2l[i2] = (short)f2bf(w - bf2f(h));
    }
}

// ---------------------------------------------------------------------------
// GEMM1 (MFMA, barrier-free): T[N,128] = X[N,256] @ W1, split-bf16 3-term.
// No LDS: A fragments (32 B/lane fp32) loaded direct from global, split in
// regs; B fragments (16 B/lane bf16) direct from L1/L2-resident Wt.
// block 256 = 4 waves; wave = 32 rows x 128 cols; zero __syncthreads.
// ---------------------------------------------------------------------------
__global__ __launch_bounds__(256) void gemm1_mfma(const float* __restrict__ X,
                                                  const short* __restrict__ Wth,
                                                  const short* __restrict__ Wtl,
                                                  bf16_t* __restrict__ T,
                                                  int nrows) {
    const int t = threadIdx.x;
    const int row0 = blockIdx.x * 128;
    const int w = t >> 6;
    const int lane = t & 63;
    const int m = lane & 15;
    const int q = lane >> 4;

    const int r0 = row0 + w * 32 + m;        // A row for mt=0
    const int r1 = r0 + 16;                  // A row for mt=1
    const bool ok0 = r0 < nrows, ok1 = r1 < nrows;
    const float* pa0 = X + (long long)r0 * F_IN + q * 8;
    const float* pa1 = X + (long long)r1 * F_IN + q * 8;

    float4v acc[2][8];
#pragma unroll
    for (int i = 0; i < 2; ++i)
#pragma unroll
        for (int j = 0; j < 8; ++j) acc[i][j] = {0.f, 0.f, 0.f, 0.f};

#pragma unroll
    for (int ks = 0; ks < 8; ++ks) {
        const int k0 = ks * 32;
        float a0f[8] = {0,0,0,0,0,0,0,0}, a1f[8] = {0,0,0,0,0,0,0,0};
        if (ok0) {
            float4 u0 = *(const float4*)(pa0 + k0);
            float4 u1 = *(const float4*)(pa0 + k0 + 4);
            a0f[0]=u0.x; a0f[1]=u0.y; a0f[2]=u0.z; a0f[3]=u0.w;
            a0f[4]=u1.x; a0f[5]=u1.y; a0f[6]=u1.z; a0f[7]=u1.w;
        }
        if (ok1) {
            float4 u0 = *(const float4*)(pa1 + k0);
            float4 u1 = *(const float4*)(pa1 + k0 + 4);
            a1f[0]=u0.x; a1f[1]=u0.y; a1f[2]=u0.z; a1f[3]=u0.w;
            a1f[4]=u1.x; a1f[5]=u1.y; a1f[6]=u1.z; a1f[7]=u1.w;
        }
        short8 ah0, al0, ah1, al1;
        split8(a0f, &ah0, &al0);
        split8(a1f, &ah1, &al1);
        const int kb = k0 + q * 8;
#pragma unroll
        for (int nc = 0; nc < 8; ++nc) {
            const int n = nc * 16 + m;
            short8 bh = *(const short8*)&Wth[n * F_IN + kb];
            short8 bl = *(const short8*)&Wtl[n * F_IN + kb];
            acc[0][nc] = mfma16(ah0, bh, acc[0][nc]);
            acc[0][nc] = mfma16(al0, bh, acc[0][nc]);
            acc[0][nc] = mfma16(ah0, bl, acc[0][nc]);
            acc[1][nc] = mfma16(ah1, bh, acc[1][nc]);
            acc[1][nc] = mfma16(al1, bh, acc[1][nc]);
            acc[1][nc] = mfma16(ah1, bl, acc[1][nc]);
        }
    }
    // epilogue: C/D layout col=lane&15, row=(lane>>4)*4+reg
#pragma unroll
    for (int mt = 0; mt < 2; ++mt)
#pragma unroll
        for (int nc = 0; nc < 8; ++nc)
#pragma unroll
            for (int reg = 0; reg < 4; ++reg) {
                int grow = row0 + w * 32 + mt * 16 + q * 4 + reg;
                int gcol = nc * 16 + m;
                if (grow < nrows)
                    T[(long long)grow * H_DIM + gcol] = f2bf(acc[mt][nc][reg]);
            }
}

// ---------------------------------------------------------------------------
// GEMM2 (MFMA, barrier-free): T2[N,64] = relu(AGG1[N,128]+b1) @ W2
// ---------------------------------------------------------------------------
__global__ __launch_bounds__(256) void gemm2_mfma(const float* __restrict__ A,
                                                  const float* __restrict__ b1,
                                                  const short* __restrict__ Wth,
                                                  const short* __restrict__ Wtl,
                                                  bf16_t* __restrict__ T,
                                                  int nrows) {
    const int t = threadIdx.x;
    const int row0 = blockIdx.x * 128;
    const int w = t >> 6;
    const int lane = t & 63;
    const int m = lane & 15;
    const int q = lane >> 4;

    const int r0 = row0 + w * 32 + m;
    const int r1 = r0 + 16;
    const bool ok0 = r0 < nrows, ok1 = r1 < nrows;
    const float* pa0 = A + (long long)r0 * H_DIM + q * 8;
    const float* pa1 = A + (long long)r1 * H_DIM + q * 8;

    float4v acc[2][4];
#pragma unroll
    for (int i = 0; i < 2; ++i)
#pragma unroll
        for (int j = 0; j < 4; ++j) acc[i][j] = {0.f, 0.f, 0.f, 0.f};

#pragma unroll
    for (int ks = 0; ks < 4; ++ks) {
        const int k0 = ks * 32;
        float bb[8];
        {
            float4 u0 = *(const float4*)&b1[k0 + q * 8];
            float4 u1 = *(const float4*)&b1[k0 + q * 8 + 4];
            bb[0]=u0.x; bb[1]=u0.y; bb[2]=u0.z; bb[3]=u0.w;
            bb[4]=u1.x; bb[5]=u1.y; bb[6]=u1.z; bb[7]=u1.w;
        }
        float a0f[8] = {0,0,0,0,0,0,0,0}, a1f[8] = {0,0,0,0,0,0,0,0};
        if (ok0) {
            float4 u0 = *(const float4*)(pa0 + k0);
            float4 u1 = *(const float4*)(pa0 + k0 + 4);
            a0f[0]=fmaxf(u0.x+bb[0],0.f); a0f[1]=fmaxf(u0.y+bb[1],0.f);
            a0f[2]=fmaxf(u0.z+bb[2],0.f); a0f[3]=fmaxf(u0.w+bb[3],0.f);
            a0f[4]=fmaxf(u1.x+bb[4],0.f); a0f[5]=fmaxf(u1.y+bb[5],0.f);
            a0f[6]=fmaxf(u1.z+bb[6],0.f); a0f[7]=fmaxf(u1.w+bb[7],0.f);
        }
        if (ok1) {
            float4 u0 = *(const float4*)(pa1 + k0);
            float4 u1 = *(const float4*)(pa1 + k0 + 4);
            a1f[0]=fmaxf(u0.x+bb[0],0.f); a1f[1]=fmaxf(u0.y+bb[1],0.f);
            a1f[2]=fmaxf(u0.z+bb[2],0.f); a1f[3]=fmaxf(u0.w+bb[3],0.f);
            a1f[4]=fmaxf(u1.x+bb[4],0.f); a1f[5]=fmaxf(u1.y+bb[5],0.f);
            a1f[6]=fmaxf(u1.z+bb[6],0.f); a1f[7]=fmaxf(u1.w+bb[7],0.f);
        }
        short8 ah0, al0, ah1, al1;
        split8(a0f, &ah0, &al0);
        split8(a1f, &ah1, &al1);
        const int kb = k0 + q * 8;
#pragma unroll
        for (int nc = 0; nc < 4; ++nc) {
            const int n = nc * 16 + m;
            short8 bh = *(const short8*)&Wth[n * H_DIM + kb];
            short8 bl = *(const short8*)&Wtl[n * H_DIM + kb];
            acc[0][nc] = mfma16(ah0, bh, acc[0][nc]);
            acc[0][nc] = mfma16(al0, bh, acc[0][nc]);
            acc[0][nc] = mfma16(ah0, bl, acc[0][nc]);
            acc[1][nc] = mfma16(ah1, bh, acc[1][nc]);
            acc[1][nc] = mfma16(al1, bh, acc[1][nc]);
            acc[1][nc] = mfma16(ah1, bl, acc[1][nc]);
        }
    }
#pragma unroll
    for (int mt = 0; mt < 2; ++mt)
#pragma unroll
        for (int nc = 0; nc < 4; ++nc)
#pragma unroll
            for (int reg = 0; reg < 4; ++reg) {
                int grow = row0 + w * 32 + mt * 16 + q * 4 + reg;
                int gcol = nc * 16 + m;
                if (grow < nrows)
                    T[(long long)grow * C_DIM + gcol] = f2bf(acc[mt][nc][reg]);
            }
}

// ---------------------------------------------------------------------------
// Gather aggregation over bf16 t: thread = (node, 8-elem chunk q).
// ---------------------------------------------------------------------------
__device__ inline void fma8_bf16(float* acc, uint4 u, float c) {
#pragma unroll
    for (int p = 0; p < 4; ++p) {
        unsigned w = (&u.x)[p];
        float lo = __uint_as_float(w << 16);
        float hi = __uint_as_float(w & 0xffff0000u);
        acc[2 * p]     = fmaf(lo, c, acc[2 * p]);
        acc[2 * p + 1] = fmaf(hi, c, acc[2 * p + 1]);
    }
}

template <int CS, bool HAS_BIAS>
__global__ __launch_bounds__(256) void agg_kernel(const bf16_t* __restrict__ t,
                                                  const float* __restrict__ dis,
                                                  const int* __restrict__ row_ptr,
                                                  const int* __restrict__ csr_src,
                                                  const float* __restrict__ bias,
                                                  float* __restrict__ agg) {
    unsigned idx = blockIdx.x * 256u + threadIdx.x;
    if (idx >= (unsigned)(N_NODES << CS)) return;
    int node = idx >> CS;
    int q = idx & ((1 << CS) - 1);
    const uint4* tv = (const uint4*)t;
    float dd = dis[node];
    int beg = row_ptr[node], end = row_ptr[node + 1];

    float acc[8];
#pragma unroll
    for (int p = 0; p < 8; ++p) acc[p] = 0.0f;
    fma8_bf16(acc, tv[idx], dd * dd);  // self-loop term

    int j = beg;
    for (; j + 3 < end; j += 4) {
        int s0 = csr_src[j + 0], s1 = csr_src[j + 1];
        int s2 = csr_src[j + 2], s3 = csr_src[j + 3];
        float c0 = dis[s0] * dd, c1 = dis[s1] * dd;
        float c2 = dis[s2] * dd, c3 = dis[s3] * dd;
        uint4 u0 = tv[((unsigned)s0 << CS) + q];
        uint4 u1 = tv[((unsigned)s1 << CS) + q];
        uint4 u2 = tv[((unsigned)s2 << CS) + q];
        uint4 u3 = tv[((unsigned)s3 << CS) + q];
        fma8_bf16(acc, u0, c0);
        fma8_bf16(acc, u1, c1);
        fma8_bf16(acc, u2, c2);
        fma8_bf16(acc, u3, c3);
    }
    for (; j < end; ++j) {
        int s = csr_src[j];
        float c = dis[s] * dd;
        fma8_bf16(acc, tv[((unsigned)s << CS) + q], c);
    }

    if (HAS_BIAS) {
        float4 bv0 = ((const float4*)bias)[q * 2];
        float4 bv1 = ((const float4*)bias)[q * 2 + 1];
        acc[0] += bv0.x; acc[1] += bv0.y; acc[2] += bv0.z; acc[3] += bv0.w;
        acc[4] += bv1.x; acc[5] += bv1.y; acc[6] += bv1.z; acc[7] += bv1.w;
    }
    float4 o0 = make_float4(acc[0], acc[1], acc[2], acc[3]);
    float4 o1 = make_float4(acc[4], acc[5], acc[6], acc[7]);
    ((float4*)agg)[idx * 2]     = o0;
    ((float4*)agg)[idx * 2 + 1] = o1;
}

// ---------------------------------------------------------------------------
// Scoring: 16 lanes per test edge (4 edges/wave); float4 loads, width-16 reduce
// ---------------------------------------------------------------------------
__global__ __launch_bounds__(256) void score_kernel(const float* __restrict__ h2,
                                                    const int* __restrict__ pos,
                                                    const int* __restrict__ neg,
                                                    float* __restrict__ out) {
    int tid = blockIdx.x * 256 + threadIdx.x;
    int e = tid >> 4;
    int q = tid & 15;
    if (e >= 2 * EP_EDGES) return;
    int i, j;
    if (e < EP_EDGES) {
        j = pos[e];
        i = pos[EP_EDGES + e];
    } else {
        j = neg[e - EP_EDGES];
        i = neg[e];
    }
    float4 a = ((const float4*)h2)[i * (C_DIM / 4) + q];
    float4 b = ((const float4*)h2)[j * (C_DIM / 4) + q];
    float v = a.x * b.x + a.y * b.y + a.z * b.z + a.w * b.w;
    v += __shfl_down(v, 8, 16);
    v += __shfl_down(v, 4, 16);
    v += __shfl_down(v, 2, 16);
    v += __shfl_down(v, 1, 16);
    if (q == 0) out[e] = v;
}

// ---------------------------------------------------------------------------
extern "C" void kernel_launch(void* const* d_in, const int* in_sizes, int n_in,
                              void* d_out, int out_size, void* d_ws, size_t ws_size,
                              hipStream_t stream) {
    const float* x  = (const float*)d_in[0];
    const int* pos  = (const int*)d_in[2];
    const int* neg  = (const int*)d_in[3];
    const int* ei   = (const int*)d_in[4];
    const float* W1 = (const float*)d_in[5];
    const float* b1 = (const float*)d_in[6];
    const float* W2 = (const float*)d_in[7];
    const float* b2 = (const float*)d_in[8];
    float* out = (float*)d_out;

    char* ws = (char*)d_ws;
    float*  dis     = (float*) (ws + 0);          //   400,000 B
    int*    row_ptr = (int*)   (ws + 400000);     //   400,004 B
    int*    bsize   = (int*)   (ws + 800128);     //     1,564 B
    int*    bbase   = (int*)   (ws + 801792);     //     1,568 B
    int*    bcursor = (int*)   (ws + 803456);     //     1,564 B
    int*    csr_src = (int*)   (ws + 805120);     // 6,400,000 B
    int2*   pairs   = (int2*)  (ws + 7205120);    // 12,800,000 B
    bf16_t* t       = (bf16_t*)(ws + 20005120);   // 25,600,000 B (N*128 bf16)
    float*  agg     = (float*) (ws + 45605120);   // 51,200,000 B (N*128 fp32)
    short*  w1th    = (short*) (ws + 96805120);   // 65,536 B
    short*  w1tl    = (short*) (ws + 96870656);   // 65,536 B
    short*  w2th    = (short*) (ws + 96936192);   // 16,384 B
    short*  w2tl    = (short*) (ws + 96952576);   // 16,384 B -> end 96,968,960

    const int* esrc = ei;
    const int* edst = ei + E_EDGES;

    // ---- CSR build v2 (bucketed; produces row_ptr, dis, csr_src) ----
    hipMemsetAsync(bsize, 0, NBUK * sizeof(int), stream);
    bhist_kernel<<<(E_EDGES + EPB - 1) / EPB, 256, 0, stream>>>(edst, bsize);
    bscan_kernel<<<1, 512, 0, stream>>>(bsize, bbase, bcursor);
    bucket_scatter_kernel<<<(E_EDGES + EPB - 1) / EPB, 256, 0, stream>>>(
        esrc, edst, bcursor, pairs);
    bucket_sort_kernel<<<NBUK, 256, 0, stream>>>(pairs, bbase, row_ptr, dis, csr_src);
    wprep_kernel<<<(H_DIM * F_IN + C_DIM * H_DIM + 255) / 256, 256, 0, stream>>>(
        W1, W2, w1th, w1tl, w2th, w2tl);

    // ---- layer 1 ----
    gemm1_mfma<<<(N_NODES + 127) / 128, 256, 0, stream>>>(x, w1th, w1tl, t, N_NODES);
    agg_kernel<4, false><<<(N_NODES * 16 + 255) / 256, 256, 0, stream>>>(
        t, dis, row_ptr, csr_src, nullptr, agg);

    // ---- layer 2 ----
    gemm2_mfma<<<(N_NODES + 127) / 128, 256, 0, stream>>>(agg, b1, w2th, w2tl, t, N_NODES);
    agg_kernel<3, true><<<(N_NODES * 8 + 255) / 256, 256, 0, stream>>>(
        t, dis, row_ptr, csr_src, b2, agg);

    // ---- scoring (16 lanes/edge) ----
    score_kernel<<<(2 * EP_EDGES * 16) / 256, 256, 0, stream>>>(agg, pos, neg, out);

    // second output: zeros [2, 2*EP]
    hipMemsetAsync(out + 2 * EP_EDGES, 0, (size_t)4 * EP_EDGES * sizeof(float), stream);
}